// Round 17
// baseline (269.988 us; speedup 1.0000x reference)
//
#include <hip/hip_runtime.h>
#include <hip/hip_bf16.h>

// CustomModel_60851096649964: two-stage biased top-k attention, folded weights.
// R17 = R13 (best, 249.6us) with ONE change: gemm2 (y = u@VP1, N=128, K=1024)
// uses BM=64 tiles (grid 450 -> all 256 CUs filled, ~2 blk/CU) instead of
// BM=128 grid 225 (1 blk/CU, 31 CUs idle, staging latency fully exposed).
// Everything else byte-identical to R13.

typedef __attribute__((ext_vector_type(4))) float f32x4;
typedef __attribute__((ext_vector_type(8))) short bf16x8v;
typedef __attribute__((ext_vector_type(4))) short short4v;

#define BT_N 2880
#define A_N  10
#define M_N  350
#define BQ_N (BT_N * A_N)   // 28800
#define DIMC 128

static __device__ __forceinline__ short f2b(float x) {
    __hip_bfloat16 b = __float2bfloat16(x);
    return __builtin_bit_cast(short, b);
}
static __device__ __forceinline__ float b2f(short s) {
    unsigned u = ((unsigned)(unsigned short)s) << 16;
    return __builtin_bit_cast(float, u);
}

// ---------------------------------------------------------------------------
// K0: folded per-head matrices (bf16). (R13 verbatim)
// ---------------------------------------------------------------------------
__global__ __launch_bounds__(256) void precompute_mats(
    const float* __restrict__ Wq, const float* __restrict__ Wk,
    const float* __restrict__ Wv, const float* __restrict__ Wcp,
    const float* __restrict__ Wc, const float* __restrict__ Wsp,
    short* __restrict__ S1t, short* __restrict__ VP1t,
    short* __restrict__ S2t, short* __restrict__ VP2z)
{
    int gid = blockIdx.x * 256 + threadIdx.x;
    int mat = gid >> 17;
    int idx = gid & 131071;
    float acc = 0.f;
    if (mat == 0) {
        int n = idx >> 7, c = idx & 127;
        int h = n >> 7, d = n & 127;
        #pragma unroll
        for (int t = 0; t < 16; ++t)
            acc += Wq[c * 128 + h * 16 + t] * Wk[d * 128 + h * 16 + t];
        S1t[idx] = f2b(acc * 0.25f);
    } else if (mat == 1) {
        int d = idx >> 10, o = idx & 1023;
        int h = o >> 7, c = o & 127;
        #pragma unroll
        for (int t = 0; t < 16; ++t)
            acc += Wv[c * 128 + h * 16 + t] * Wcp[(h * 16 + t) * 128 + d];
        VP1t[idx] = f2b(acc);
    } else if (mat == 2) {
        int n = idx >> 7, c = idx & 127;
        int h = n >> 7, d = n & 127;
        #pragma unroll
        for (int t = 0; t < 16; ++t)
            acc += Wc[c * 384 + h * 16 + t] * Wc[d * 384 + 128 + h * 16 + t];
        S2t[idx] = f2b(acc * 0.25f);
    } else {
        // VP2z[n=h*128+d][c] = sum_t Wc[c][256+h16+t] * Wsp[h16+t][d]
        int n = idx >> 7, c = idx & 127;
        int h = n >> 7, d = n & 127;
        #pragma unroll
        for (int t = 0; t < 16; ++t)
            acc += Wc[c * 384 + 256 + h * 16 + t] * Wsp[(h * 16 + t) * 128 + d];
        VP2z[idx] = f2b(acc);
    }
}

// ---------------------------------------------------------------------------
__global__ __launch_bounds__(256) void conv_bf16(
    const float* __restrict__ in, short* __restrict__ out)
{
    int i = blockIdx.x * 256 + threadIdx.x;
    f32x4 a = ((const f32x4*)in)[2 * i];
    f32x4 b = ((const f32x4*)in)[2 * i + 1];
    bf16x8v t;
    t[0] = f2b(a.x); t[1] = f2b(a.y); t[2] = f2b(a.z); t[3] = f2b(a.w);
    t[4] = f2b(b.x); t[5] = f2b(b.y); t[6] = f2b(b.z); t[7] = f2b(b.w);
    ((bf16x8v*)out)[i] = t;
}

// ---------------------------------------------------------------------------
// bf16 MFMA GEMM, C[M,N] = A[M,K] @ Bt^T. BM=BN=128, BK=64. (R13 verbatim)
// ---------------------------------------------------------------------------
template<bool CF32>
__global__ __launch_bounds__(256) void gemm_bt(
    const short* __restrict__ Ap, const short* __restrict__ Bt,
    void* __restrict__ Cp, int M, int N, int K)
{
    __shared__ short As[128][72];
    __shared__ short Bs[128][72];
    const int tid  = threadIdx.x;
    const int bm   = blockIdx.y << 7, bn = blockIdx.x << 7;
    const int wave = tid >> 6, lane = tid & 63;
    const int wm   = (wave >> 1) << 6, wn = (wave & 1) << 6;
    const int row16 = lane & 15, kq = (lane >> 4) << 3;
    f32x4 acc[4][4] = {};

    for (int k0 = 0; k0 < K; k0 += 64) {
        #pragma unroll
        for (int i = 0; i < 4; ++i) {
            int g = (i << 8) + tid;
            int r = g >> 3, c = (g & 7) << 3;
            *(bf16x8v*)&As[r][c] = *(const bf16x8v*)(Ap + (size_t)(bm + r) * K + k0 + c);
        }
        #pragma unroll
        for (int i = 0; i < 4; ++i) {
            int g = (i << 8) + tid;
            int r = g >> 3, c = (g & 7) << 3;
            *(bf16x8v*)&Bs[r][c] = *(const bf16x8v*)(Bt + (size_t)(bn + r) * K + k0 + c);
        }
        __syncthreads();
        #pragma unroll
        for (int kk = 0; kk < 64; kk += 32) {
            bf16x8v afr[4], bfr[4];
            #pragma unroll
            for (int mi = 0; mi < 4; ++mi)
                afr[mi] = *(const bf16x8v*)&As[wm + (mi << 4) + row16][kq + kk];
            #pragma unroll
            for (int ni = 0; ni < 4; ++ni)
                bfr[ni] = *(const bf16x8v*)&Bs[wn + (ni << 4) + row16][kq + kk];
            #pragma unroll
            for (int mi = 0; mi < 4; ++mi)
                #pragma unroll
                for (int ni = 0; ni < 4; ++ni)
                    acc[mi][ni] = __builtin_amdgcn_mfma_f32_16x16x32_bf16(
                        afr[mi], bfr[ni], acc[mi][ni], 0, 0, 0);
        }
        __syncthreads();
    }

    const int col = lane & 15, rb = (lane >> 4) << 2;
    #pragma unroll
    for (int mi = 0; mi < 4; ++mi)
        #pragma unroll
        for (int ni = 0; ni < 4; ++ni)
            #pragma unroll
            for (int r = 0; r < 4; ++r) {
                int rr = bm + wm + (mi << 4) + rb + r;
                int cc = bn + wn + (ni << 4) + col;
                float v = acc[mi][ni][r];
                if (CF32) ((float*)Cp)[(size_t)rr * N + cc] = v;
                else      ((short*)Cp)[(size_t)rr * N + cc] = f2b(v);
            }
}

// ---------------------------------------------------------------------------
// BM=64 variant for the N=128 GEMM (grid 450 -> all CUs busy, 2 blk/CU).
// Same BK=64 K-order and rounding as gemm_bt -> bit-identical output.
// ---------------------------------------------------------------------------
__global__ __launch_bounds__(256) void gemm_bt64(
    const short* __restrict__ Ap, const short* __restrict__ Bt,
    short* __restrict__ Cp, int M, int N, int K)
{
    __shared__ short As[64][72];
    __shared__ short Bs[128][72];
    const int tid  = threadIdx.x;
    const int bm   = blockIdx.y << 6, bn = blockIdx.x << 7;
    const int wave = tid >> 6, lane = tid & 63;
    const int wm   = (wave >> 1) << 5, wn = (wave & 1) << 6;
    const int row16 = lane & 15, kq = (lane >> 4) << 3;
    f32x4 acc[2][4] = {};

    for (int k0 = 0; k0 < K; k0 += 64) {
        #pragma unroll
        for (int i = 0; i < 2; ++i) {
            int g = (i << 8) + tid;
            int r = g >> 3, c = (g & 7) << 3;
            *(bf16x8v*)&As[r][c] = *(const bf16x8v*)(Ap + (size_t)(bm + r) * K + k0 + c);
        }
        #pragma unroll
        for (int i = 0; i < 4; ++i) {
            int g = (i << 8) + tid;
            int r = g >> 3, c = (g & 7) << 3;
            *(bf16x8v*)&Bs[r][c] = *(const bf16x8v*)(Bt + (size_t)(bn + r) * K + k0 + c);
        }
        __syncthreads();
        #pragma unroll
        for (int kk = 0; kk < 64; kk += 32) {
            bf16x8v afr[2], bfr[4];
            #pragma unroll
            for (int mi = 0; mi < 2; ++mi)
                afr[mi] = *(const bf16x8v*)&As[wm + (mi << 4) + row16][kq + kk];
            #pragma unroll
            for (int ni = 0; ni < 4; ++ni)
                bfr[ni] = *(const bf16x8v*)&Bs[wn + (ni << 4) + row16][kq + kk];
            #pragma unroll
            for (int mi = 0; mi < 2; ++mi)
                #pragma unroll
                for (int ni = 0; ni < 4; ++ni)
                    acc[mi][ni] = __builtin_amdgcn_mfma_f32_16x16x32_bf16(
                        afr[mi], bfr[ni], acc[mi][ni], 0, 0, 0);
        }
        __syncthreads();
    }

    const int col = lane & 15, rb = (lane >> 4) << 2;
    #pragma unroll
    for (int mi = 0; mi < 2; ++mi)
        #pragma unroll
        for (int ni = 0; ni < 4; ++ni)
            #pragma unroll
            for (int r = 0; r < 4; ++r) {
                int rr = bm + wm + (mi << 4) + rb + r;
                int cc = bn + wn + (ni << 4) + col;
                Cp[(size_t)rr * N + cc] = f2b(acc[mi][ni][r]);
            }
}

// ---------------------------------------------------------------------------
// Cross attention v3 (R9/R13 verbatim): MFMA score, bf16 mrows, XCD-swizzled.
// ---------------------------------------------------------------------------
__global__ __launch_bounds__(256) void attn_cross(
    const float* __restrict__ m_token, const short* __restrict__ qS,
    const float* __restrict__ pe, const int* __restrict__ rel,
    short* __restrict__ u)
{
    __shared__ short mrows[32][136];
    __shared__ short qsr[16][136];
    __shared__ float sc[32][17];
    __shared__ float wts[8][33];
    __shared__ float peL[256];
    __shared__ int   selk[32];

    const int phys = blockIdx.x;
    const int b    = (phys & 7) * 360 + (phys >> 3) / A_N;
    const int q    = (phys >> 3) % A_N;
    const int bq   = b * A_N + q;
    const int tid  = threadIdx.x;
    const int wave = tid >> 6, lane = tid & 63;
    const int row16 = lane & 15, kq8 = (lane >> 4) << 3;

    const int* relrow = rel + (size_t)bq * M_N;
    for (int k = tid; k < M_N; k += 256) {
        int r = relrow[k];
        if (r >= 0) selk[r] = k;
    }
    if (tid < 128) {
        int h = tid >> 4, c8 = (tid & 15) << 3;
        *(bf16x8v*)&qsr[h][c8] = *(const bf16x8v*)(qS + (size_t)bq * 1024 + h * 128 + c8);
    }
    for (int g = tid; g < 1088; g += 256) ((short*)qsr)[1088 + g] = 0;
    peL[tid] = pe[(size_t)bq * 256 + tid];
    __syncthreads();

    {
        int r = tid >> 3, c16 = (tid & 7) << 4;
        const float* src = m_token + ((size_t)b * M_N + selk[r]) * DIMC + c16;
        f32x4 v0 = *(const f32x4*)(src);
        f32x4 v1 = *(const f32x4*)(src + 4);
        f32x4 v2 = *(const f32x4*)(src + 8);
        f32x4 v3 = *(const f32x4*)(src + 12);
        bf16x8v t0, t1;
        t0[0] = f2b(v0.x); t0[1] = f2b(v0.y); t0[2] = f2b(v0.z); t0[3] = f2b(v0.w);
        t0[4] = f2b(v1.x); t0[5] = f2b(v1.y); t0[6] = f2b(v1.z); t0[7] = f2b(v1.w);
        t1[0] = f2b(v2.x); t1[1] = f2b(v2.y); t1[2] = f2b(v2.z); t1[3] = f2b(v2.w);
        t1[4] = f2b(v3.x); t1[5] = f2b(v3.y); t1[6] = f2b(v3.z); t1[7] = f2b(v3.w);
        *(bf16x8v*)&mrows[r][c16]     = t0;
        *(bf16x8v*)&mrows[r][c16 + 8] = t1;
    }
    __syncthreads();

    if (wave < 2) {
        f32x4 acc = {0.f, 0.f, 0.f, 0.f};
        #pragma unroll
        for (int kc = 0; kc < 4; ++kc) {
            bf16x8v a  = *(const bf16x8v*)&mrows[(wave << 4) + row16][(kc << 5) + kq8];
            bf16x8v bb = *(const bf16x8v*)&qsr[row16][(kc << 5) + kq8];
            acc = __builtin_amdgcn_mfma_f32_16x16x32_bf16(a, bb, acc, 0, 0, 0);
        }
        const int rb4 = (lane >> 4) << 2;
        #pragma unroll
        for (int r = 0; r < 4; ++r)
            sc[(wave << 4) + rb4 + r][row16] = acc[r];
    }
    __syncthreads();

    {
        const int h = tid >> 5, r = tid & 31;
        float s = sc[r][h] + peL[r * 8 + h];
        float mx = s;
        #pragma unroll
        for (int off = 16; off; off >>= 1) mx = fmaxf(mx, __shfl_xor(mx, off, 32));
        float e = __expf(s - mx);
        float su = e;
        #pragma unroll
        for (int off = 16; off; off >>= 1) su += __shfl_xor(su, off, 32);
        wts[h][r] = e / su;
    }
    __syncthreads();

    {
        const int h = tid >> 5, d0 = (tid << 2) & 127;
        f32x4 acc = {0.f, 0.f, 0.f, 0.f};
        #pragma unroll
        for (int r = 0; r < 32; ++r) {
            float w = wts[h][r];
            short4v mv = *(const short4v*)&mrows[r][d0];
            acc.x += w * b2f(mv.x);
            acc.y += w * b2f(mv.y);
            acc.z += w * b2f(mv.z);
            acc.w += w * b2f(mv.w);
        }
        short4v t;
        t.x = f2b(acc.x); t.y = f2b(acc.y); t.z = f2b(acc.z); t.w = f2b(acc.w);
        *(short4v*)(u + (size_t)bq * 1024 + (tid << 2)) = t;
    }
}

// ---------------------------------------------------------------------------
// tail_fused (R13 verbatim): per block = 4 batches.
// ---------------------------------------------------------------------------
__global__ __launch_bounds__(256) void tail_fused(
    const short* __restrict__ ybf, const short* __restrict__ S2t,
    const short* __restrict__ VP2z, const float* __restrict__ pe,
    const int* __restrict__ rel, float* __restrict__ outp)
{
    __shared__ short yL[48][136];
    __shared__ short TL[48][136];
    __shared__ short Bs[64][136];
    __shared__ float sw[4][10][3];
    __shared__ float peL[960];
    __shared__ int   selS[120];

    const int tid  = threadIdx.x;
    const int wave = tid >> 6, lane = tid & 63;
    const int row16 = lane & 15, kq8 = (lane >> 4) << 3, rb4 = (lane >> 4) << 2;
    const int B0row = blockIdx.x * 40;

    for (int g = tid; g < 640; g += 256) {
        int r = g >> 4, c8 = (g & 15) << 3;
        *(bf16x8v*)&yL[r][c8] = *(const bf16x8v*)(ybf + (size_t)(B0row + r) * 128 + c8);
    }
    for (int g = tid; g < 1088; g += 256) ((short*)yL)[40 * 136 + g] = 0;
    for (int g = tid; g < 400; g += 256) {
        int v = rel[(size_t)blockIdx.x * 400 + g];
        if (v >= 0) {
            int bb = g / 100, rem = g - bb * 100;
            int q = rem / 10, k = rem - q * 10;
            selS[bb * 30 + q * 3 + v] = k;
        }
    }
    for (int g = tid; g < 960; g += 256) peL[g] = pe[(size_t)blockIdx.x * 960 + g];
    __syncthreads();

    bf16x8v af[3][4];
    #pragma unroll
    for (int mt = 0; mt < 3; ++mt)
        #pragma unroll
        for (int kk = 0; kk < 4; ++kk)
            af[mt][kk] = *(const bf16x8v*)&yL[(mt << 4) + row16][(kk << 5) + kq8];

    f32x4 acc_out[5] = {};

    for (int h = 0; h < 8; ++h) {
        #pragma unroll
        for (int dh = 0; dh < 2; ++dh) {
            __syncthreads();
            #pragma unroll
            for (int i = 0; i < 4; ++i) {
                int g = (i << 8) + tid;
                int r = g >> 4, c8 = (g & 15) << 3;
                *(bf16x8v*)&Bs[r][c8] =
                    *(const bf16x8v*)(S2t + (size_t)(h * 128 + dh * 64 + r) * 128 + c8);
            }
            __syncthreads();
            bf16x8v bfr[4];
            #pragma unroll
            for (int kk = 0; kk < 4; ++kk)
                bfr[kk] = *(const bf16x8v*)&Bs[(wave << 4) + row16][(kk << 5) + kq8];
            f32x4 gacc[3] = {};
            #pragma unroll
            for (int mt = 0; mt < 3; ++mt)
                #pragma unroll
                for (int kk = 0; kk < 4; ++kk)
                    gacc[mt] = __builtin_amdgcn_mfma_f32_16x16x32_bf16(
                        af[mt][kk], bfr[kk], gacc[mt], 0, 0, 0);
            #pragma unroll
            for (int mt = 0; mt < 3; ++mt)
                #pragma unroll
                for (int r = 0; r < 4; ++r) {
                    int a = (mt << 4) + rb4 + r;
                    if (a < 40) TL[a][(dh << 6) + (wave << 4) + row16] = f2b(gacc[mt][r]);
                }
        }
        __syncthreads();

        if (tid < 120) {
            int bb = tid / 30, rem = tid - bb * 30, q = rem / 3, r = rem - q * 3;
            int k = selS[bb * 30 + q * 3 + r];
            const short* gq = &TL[bb * 10 + q][0];
            const short* yk = &yL[bb * 10 + k][0];
            float s = 0.f;
            #pragma unroll
            for (int d = 0; d < 128; d += 4) {
                short4v gv = *(const short4v*)(gq + d);
                short4v yv = *(const short4v*)(yk + d);
                s += b2f(gv.x) * b2f(yv.x) + b2f(gv.y) * b2f(yv.y)
                   + b2f(gv.z) * b2f(yv.z) + b2f(gv.w) * b2f(yv.w);
            }
            sw[bb][q][r] = s + peL[bb * 240 + q * 24 + r * 8 + h];
        }
        __syncthreads();
        if (tid < 40) {
            int bb = tid / 10, q = tid - bb * 10;
            float s0 = sw[bb][q][0], s1 = sw[bb][q][1], s2 = sw[bb][q][2];
            float mx = fmaxf(s0, fmaxf(s1, s2));
            float e0 = __expf(s0 - mx), e1 = __expf(s1 - mx), e2 = __expf(s2 - mx);
            float inv = 1.f / (e0 + e1 + e2);
            sw[bb][q][0] = e0 * inv; sw[bb][q][1] = e1 * inv; sw[bb][q][2] = e2 * inv;
        }

        #pragma unroll
        for (int dh = 0; dh < 2; ++dh) {
            __syncthreads();
            #pragma unroll
            for (int i = 0; i < 4; ++i) {
                int g = (i << 8) + tid;
                int r = g >> 4, c8 = (g & 15) << 3;
                *(bf16x8v*)&Bs[r][c8] =
                    *(const bf16x8v*)(VP2z + (size_t)(h * 128 + dh * 64 + r) * 128 + c8);
            }
            __syncthreads();
            bf16x8v bfr[4];
            #pragma unroll
            for (int kk = 0; kk < 4; ++kk)
                bfr[kk] = *(const bf16x8v*)&Bs[(wave << 4) + row16][(kk << 5) + kq8];
            f32x4 zacc[3] = {};
            #pragma unroll
            for (int mt = 0; mt < 3; ++mt)
                #pragma unroll
                for (int kk = 0; kk < 4; ++kk)
                    zacc[mt] = __builtin_amdgcn_mfma_f32_16x16x32_bf16(
                        af[mt][kk], bfr[kk], zacc[mt], 0, 0, 0);
            #pragma unroll
            for (int mt = 0; mt < 3; ++mt)
                #pragma unroll
                for (int r = 0; r < 4; ++r) {
                    int a = (mt << 4) + rb4 + r;
                    if (a < 40) TL[a][(dh << 6) + (wave << 4) + row16] = f2b(zacc[mt][r]);
                }
        }
        __syncthreads();

        #pragma unroll
        for (int i = 0; i < 5; ++i) {
            int g = (i << 8) + tid;
            int a = g >> 5, d4 = (g & 31) << 2;
            int bb = (a * 205) >> 11, q = a - bb * 10;
            int k0 = selS[bb * 30 + q * 3 + 0];
            int k1 = selS[bb * 30 + q * 3 + 1];
            int k2 = selS[bb * 30 + q * 3 + 2];
            float w0 = sw[bb][q][0], w1 = sw[bb][q][1], w2 = sw[bb][q][2];
            short4v z0 = *(const short4v*)&TL[bb * 10 + k0][d4];
            short4v z1 = *(const short4v*)&TL[bb * 10 + k1][d4];
            short4v z2 = *(const short4v*)&TL[bb * 10 + k2][d4];
            acc_out[i].x += w0 * b2f(z0.x) + w1 * b2f(z1.x) + w2 * b2f(z2.x);
            acc_out[i].y += w0 * b2f(z0.y) + w1 * b2f(z1.y) + w2 * b2f(z2.y);
            acc_out[i].z += w0 * b2f(z0.z) + w1 * b2f(z1.z) + w2 * b2f(z2.z);
            acc_out[i].w += w0 * b2f(z0.w) + w1 * b2f(z1.w) + w2 * b2f(z2.w);
        }
    }

    #pragma unroll
    for (int i = 0; i < 5; ++i) {
        int g = (i << 8) + tid;
        int a = g >> 5, d4 = (g & 31) << 2;
        *(f32x4*)(outp + (size_t)(B0row + a) * 128 + d4) = acc_out[i];
    }
}

// ---------------------------------------------------------------------------
extern "C" void kernel_launch(void* const* d_in, const int* in_sizes, int n_in,
                              void* d_out, int out_size, void* d_ws, size_t ws_size,
                              hipStream_t stream)
{
    const float* a_token = (const float*)d_in[0];
    const float* m_token = (const float*)d_in[1];
    const float* a2m_pe  = (const float*)d_in[2];
    const float* a_pe    = (const float*)d_in[3];
    const float* Wq      = (const float*)d_in[4];
    const float* Wk      = (const float*)d_in[5];
    const float* Wv      = (const float*)d_in[6];
    const float* Wcp     = (const float*)d_in[7];
    const float* Wc      = (const float*)d_in[8];
    const float* Wsp     = (const float*)d_in[9];
    const int*   a2m_rel = (const int*)d_in[10];
    const int*   a_rel   = (const int*)d_in[11];

    char* ws = (char*)d_ws;
    short* S1t  = (short*)(ws + 0);
    short* VP1t = (short*)(ws + 262144);
    short* S2t  = (short*)(ws + 524288);
    short* VP2z = (short*)(ws + 786432);
    short* buf1 = (short*)(ws + 1048576);                      // qS
    short* buf2 = (short*)(ws + 1048576 + 58982400ull);        // u
    short* ybf  = (short*)(ws + 1048576 + 2ull * 58982400ull); // y bf16
    short* abf  = (short*)(ws + 126386176ull);                 // a_token bf16
    float* outp = (float*)d_out;

    precompute_mats<<<dim3(2048), dim3(256), 0, stream>>>(
        Wq, Wk, Wv, Wcp, Wc, Wsp, S1t, VP1t, S2t, VP2z);

    conv_bf16<<<dim3(1800), dim3(256), 0, stream>>>(a_token, abf);

    // qS = a @ S1   [28800,1024], K=128
    gemm_bt<false><<<dim3(8, 225), dim3(256), 0, stream>>>(
        abf, S1t, (void*)buf1, BQ_N, 1024, 128);

    attn_cross<<<dim3(BQ_N), dim3(256), 0, stream>>>(
        m_token, buf1, a2m_pe, a2m_rel, buf2);

    // y = u @ VP1   [28800,128], K=1024 -- BM=64, grid 450 (the one change)
    gemm_bt64<<<dim3(1, 450), dim3(256), 0, stream>>>(
        buf2, VP1t, ybf, BQ_N, 128, 1024);

    // fused tail (R13)
    tail_fused<<<dim3(720), dim3(256), 0, stream>>>(
        ybf, S2t, VP2z, a_pe, a_rel, outp);
}

// Round 18
// 248.833 us; speedup vs baseline: 1.0850x; 1.0850x over previous
//
#include <hip/hip_runtime.h>
#include <hip/hip_bf16.h>

// CustomModel_60851096649964: two-stage biased top-k attention, folded weights.
// R18 = R13 (best, 249.6us) + two independent fixes:
//  (1) gemm2 -> 512-thread variant (8 waves = 2/SIMD at grid (1,225); the
//      diagnosed problem was 1 wave/SIMD latency exposure, not CU fill --
//      R17 proved BM=64 wrong, +20us).
//  (2) attn_cross combine: h-pair sharing (one mrows read feeds h and h+4),
//      halving combine LDS traffic. Bit-identical numerics for both.

typedef __attribute__((ext_vector_type(4))) float f32x4;
typedef __attribute__((ext_vector_type(8))) short bf16x8v;
typedef __attribute__((ext_vector_type(4))) short short4v;

#define BT_N 2880
#define A_N  10
#define M_N  350
#define BQ_N (BT_N * A_N)   // 28800
#define DIMC 128

static __device__ __forceinline__ short f2b(float x) {
    __hip_bfloat16 b = __float2bfloat16(x);
    return __builtin_bit_cast(short, b);
}
static __device__ __forceinline__ float b2f(short s) {
    unsigned u = ((unsigned)(unsigned short)s) << 16;
    return __builtin_bit_cast(float, u);
}

// ---------------------------------------------------------------------------
// K0: folded per-head matrices (bf16). (R13 verbatim)
// ---------------------------------------------------------------------------
__global__ __launch_bounds__(256) void precompute_mats(
    const float* __restrict__ Wq, const float* __restrict__ Wk,
    const float* __restrict__ Wv, const float* __restrict__ Wcp,
    const float* __restrict__ Wc, const float* __restrict__ Wsp,
    short* __restrict__ S1t, short* __restrict__ VP1t,
    short* __restrict__ S2t, short* __restrict__ VP2z)
{
    int gid = blockIdx.x * 256 + threadIdx.x;
    int mat = gid >> 17;
    int idx = gid & 131071;
    float acc = 0.f;
    if (mat == 0) {
        int n = idx >> 7, c = idx & 127;
        int h = n >> 7, d = n & 127;
        #pragma unroll
        for (int t = 0; t < 16; ++t)
            acc += Wq[c * 128 + h * 16 + t] * Wk[d * 128 + h * 16 + t];
        S1t[idx] = f2b(acc * 0.25f);
    } else if (mat == 1) {
        int d = idx >> 10, o = idx & 1023;
        int h = o >> 7, c = o & 127;
        #pragma unroll
        for (int t = 0; t < 16; ++t)
            acc += Wv[c * 128 + h * 16 + t] * Wcp[(h * 16 + t) * 128 + d];
        VP1t[idx] = f2b(acc);
    } else if (mat == 2) {
        int n = idx >> 7, c = idx & 127;
        int h = n >> 7, d = n & 127;
        #pragma unroll
        for (int t = 0; t < 16; ++t)
            acc += Wc[c * 384 + h * 16 + t] * Wc[d * 384 + 128 + h * 16 + t];
        S2t[idx] = f2b(acc * 0.25f);
    } else {
        // VP2z[n=h*128+d][c] = sum_t Wc[c][256+h16+t] * Wsp[h16+t][d]
        int n = idx >> 7, c = idx & 127;
        int h = n >> 7, d = n & 127;
        #pragma unroll
        for (int t = 0; t < 16; ++t)
            acc += Wc[c * 384 + 256 + h * 16 + t] * Wsp[(h * 16 + t) * 128 + d];
        VP2z[idx] = f2b(acc);
    }
}

// ---------------------------------------------------------------------------
__global__ __launch_bounds__(256) void conv_bf16(
    const float* __restrict__ in, short* __restrict__ out)
{
    int i = blockIdx.x * 256 + threadIdx.x;
    f32x4 a = ((const f32x4*)in)[2 * i];
    f32x4 b = ((const f32x4*)in)[2 * i + 1];
    bf16x8v t;
    t[0] = f2b(a.x); t[1] = f2b(a.y); t[2] = f2b(a.z); t[3] = f2b(a.w);
    t[4] = f2b(b.x); t[5] = f2b(b.y); t[6] = f2b(b.z); t[7] = f2b(b.w);
    ((bf16x8v*)out)[i] = t;
}

// ---------------------------------------------------------------------------
// bf16 MFMA GEMM, 256 threads, BM=BN=128, BK=64. (R13 verbatim; used for qS)
// ---------------------------------------------------------------------------
template<bool CF32>
__global__ __launch_bounds__(256) void gemm_bt(
    const short* __restrict__ Ap, const short* __restrict__ Bt,
    void* __restrict__ Cp, int M, int N, int K)
{
    __shared__ short As[128][72];
    __shared__ short Bs[128][72];
    const int tid  = threadIdx.x;
    const int bm   = blockIdx.y << 7, bn = blockIdx.x << 7;
    const int wave = tid >> 6, lane = tid & 63;
    const int wm   = (wave >> 1) << 6, wn = (wave & 1) << 6;
    const int row16 = lane & 15, kq = (lane >> 4) << 3;
    f32x4 acc[4][4] = {};

    for (int k0 = 0; k0 < K; k0 += 64) {
        #pragma unroll
        for (int i = 0; i < 4; ++i) {
            int g = (i << 8) + tid;
            int r = g >> 3, c = (g & 7) << 3;
            *(bf16x8v*)&As[r][c] = *(const bf16x8v*)(Ap + (size_t)(bm + r) * K + k0 + c);
        }
        #pragma unroll
        for (int i = 0; i < 4; ++i) {
            int g = (i << 8) + tid;
            int r = g >> 3, c = (g & 7) << 3;
            *(bf16x8v*)&Bs[r][c] = *(const bf16x8v*)(Bt + (size_t)(bn + r) * K + k0 + c);
        }
        __syncthreads();
        #pragma unroll
        for (int kk = 0; kk < 64; kk += 32) {
            bf16x8v afr[4], bfr[4];
            #pragma unroll
            for (int mi = 0; mi < 4; ++mi)
                afr[mi] = *(const bf16x8v*)&As[wm + (mi << 4) + row16][kq + kk];
            #pragma unroll
            for (int ni = 0; ni < 4; ++ni)
                bfr[ni] = *(const bf16x8v*)&Bs[wn + (ni << 4) + row16][kq + kk];
            #pragma unroll
            for (int mi = 0; mi < 4; ++mi)
                #pragma unroll
                for (int ni = 0; ni < 4; ++ni)
                    acc[mi][ni] = __builtin_amdgcn_mfma_f32_16x16x32_bf16(
                        afr[mi], bfr[ni], acc[mi][ni], 0, 0, 0);
        }
        __syncthreads();
    }

    const int col = lane & 15, rb = (lane >> 4) << 2;
    #pragma unroll
    for (int mi = 0; mi < 4; ++mi)
        #pragma unroll
        for (int ni = 0; ni < 4; ++ni)
            #pragma unroll
            for (int r = 0; r < 4; ++r) {
                int rr = bm + wm + (mi << 4) + rb + r;
                int cc = bn + wn + (ni << 4) + col;
                float v = acc[mi][ni][r];
                if (CF32) ((float*)Cp)[(size_t)rr * N + cc] = v;
                else      ((short*)Cp)[(size_t)rr * N + cc] = f2b(v);
            }
}

// ---------------------------------------------------------------------------
// 512-thread GEMM variant (8 waves = 2/SIMD) for gemm2. Same BM/BN/BK and
// K-order as gemm_bt -> bit-identical output. Wave layout 4m x 2n:
// wave w owns rows wm=(w>>1)*32..+31, cols wn=(w&1)*64..+63 (acc[2][4]).
// ---------------------------------------------------------------------------
__global__ __launch_bounds__(512) void gemm_bt512(
    const short* __restrict__ Ap, const short* __restrict__ Bt,
    short* __restrict__ Cp, int M, int N, int K)
{
    __shared__ short As[128][72];
    __shared__ short Bs[128][72];
    const int tid  = threadIdx.x;
    const int bm   = blockIdx.y << 7, bn = blockIdx.x << 7;
    const int wave = tid >> 6, lane = tid & 63;
    const int wm   = (wave >> 1) << 5;   // 0,32,64,96
    const int wn   = (wave & 1) << 6;    // 0,64
    const int row16 = lane & 15, kq = (lane >> 4) << 3;
    f32x4 acc[2][4] = {};

    for (int k0 = 0; k0 < K; k0 += 64) {
        #pragma unroll
        for (int i = 0; i < 2; ++i) {
            int g = (i << 9) + tid;
            int r = g >> 3, c = (g & 7) << 3;
            *(bf16x8v*)&As[r][c] = *(const bf16x8v*)(Ap + (size_t)(bm + r) * K + k0 + c);
        }
        #pragma unroll
        for (int i = 0; i < 2; ++i) {
            int g = (i << 9) + tid;
            int r = g >> 3, c = (g & 7) << 3;
            *(bf16x8v*)&Bs[r][c] = *(const bf16x8v*)(Bt + (size_t)(bn + r) * K + k0 + c);
        }
        __syncthreads();
        #pragma unroll
        for (int kk = 0; kk < 64; kk += 32) {
            bf16x8v afr[2], bfr[4];
            #pragma unroll
            for (int mi = 0; mi < 2; ++mi)
                afr[mi] = *(const bf16x8v*)&As[wm + (mi << 4) + row16][kq + kk];
            #pragma unroll
            for (int ni = 0; ni < 4; ++ni)
                bfr[ni] = *(const bf16x8v*)&Bs[wn + (ni << 4) + row16][kq + kk];
            #pragma unroll
            for (int mi = 0; mi < 2; ++mi)
                #pragma unroll
                for (int ni = 0; ni < 4; ++ni)
                    acc[mi][ni] = __builtin_amdgcn_mfma_f32_16x16x32_bf16(
                        afr[mi], bfr[ni], acc[mi][ni], 0, 0, 0);
        }
        __syncthreads();
    }

    const int col = lane & 15, rb = (lane >> 4) << 2;
    #pragma unroll
    for (int mi = 0; mi < 2; ++mi)
        #pragma unroll
        for (int ni = 0; ni < 4; ++ni)
            #pragma unroll
            for (int r = 0; r < 4; ++r) {
                int rr = bm + wm + (mi << 4) + rb + r;
                int cc = bn + wn + (ni << 4) + col;
                Cp[(size_t)rr * N + cc] = f2b(acc[mi][ni][r]);
            }
}

// ---------------------------------------------------------------------------
// Cross attention v3b: R13 internals, combine restructured with h-pair
// sharing (thread (hp=wave, d2=lane*2) computes h=hp and h=hp+4 from one
// mrows read). Gather/score/softmax byte-identical to R13.
// ---------------------------------------------------------------------------
__global__ __launch_bounds__(256) void attn_cross(
    const float* __restrict__ m_token, const short* __restrict__ qS,
    const float* __restrict__ pe, const int* __restrict__ rel,
    short* __restrict__ u)
{
    __shared__ short mrows[32][136];
    __shared__ short qsr[16][136];
    __shared__ float sc[32][17];
    __shared__ float wts[8][33];
    __shared__ float peL[256];
    __shared__ int   selk[32];

    const int phys = blockIdx.x;
    const int b    = (phys & 7) * 360 + (phys >> 3) / A_N;
    const int q    = (phys >> 3) % A_N;
    const int bq   = b * A_N + q;
    const int tid  = threadIdx.x;
    const int wave = tid >> 6, lane = tid & 63;
    const int row16 = lane & 15, kq8 = (lane >> 4) << 3;

    const int* relrow = rel + (size_t)bq * M_N;
    for (int k = tid; k < M_N; k += 256) {
        int r = relrow[k];
        if (r >= 0) selk[r] = k;
    }
    if (tid < 128) {
        int h = tid >> 4, c8 = (tid & 15) << 3;
        *(bf16x8v*)&qsr[h][c8] = *(const bf16x8v*)(qS + (size_t)bq * 1024 + h * 128 + c8);
    }
    for (int g = tid; g < 1088; g += 256) ((short*)qsr)[1088 + g] = 0;
    peL[tid] = pe[(size_t)bq * 256 + tid];
    __syncthreads();

    {
        int r = tid >> 3, c16 = (tid & 7) << 4;
        const float* src = m_token + ((size_t)b * M_N + selk[r]) * DIMC + c16;
        f32x4 v0 = *(const f32x4*)(src);
        f32x4 v1 = *(const f32x4*)(src + 4);
        f32x4 v2 = *(const f32x4*)(src + 8);
        f32x4 v3 = *(const f32x4*)(src + 12);
        bf16x8v t0, t1;
        t0[0] = f2b(v0.x); t0[1] = f2b(v0.y); t0[2] = f2b(v0.z); t0[3] = f2b(v0.w);
        t0[4] = f2b(v1.x); t0[5] = f2b(v1.y); t0[6] = f2b(v1.z); t0[7] = f2b(v1.w);
        t1[0] = f2b(v2.x); t1[1] = f2b(v2.y); t1[2] = f2b(v2.z); t1[3] = f2b(v2.w);
        t1[4] = f2b(v3.x); t1[5] = f2b(v3.y); t1[6] = f2b(v3.z); t1[7] = f2b(v3.w);
        *(bf16x8v*)&mrows[r][c16]     = t0;
        *(bf16x8v*)&mrows[r][c16 + 8] = t1;
    }
    __syncthreads();

    if (wave < 2) {
        f32x4 acc = {0.f, 0.f, 0.f, 0.f};
        #pragma unroll
        for (int kc = 0; kc < 4; ++kc) {
            bf16x8v a  = *(const bf16x8v*)&mrows[(wave << 4) + row16][(kc << 5) + kq8];
            bf16x8v bb = *(const bf16x8v*)&qsr[row16][(kc << 5) + kq8];
            acc = __builtin_amdgcn_mfma_f32_16x16x32_bf16(a, bb, acc, 0, 0, 0);
        }
        const int rb4 = (lane >> 4) << 2;
        #pragma unroll
        for (int r = 0; r < 4; ++r)
            sc[(wave << 4) + rb4 + r][row16] = acc[r];
    }
    __syncthreads();

    {
        const int h = tid >> 5, r = tid & 31;
        float s = sc[r][h] + peL[r * 8 + h];
        float mx = s;
        #pragma unroll
        for (int off = 16; off; off >>= 1) mx = fmaxf(mx, __shfl_xor(mx, off, 32));
        float e = __expf(s - mx);
        float su = e;
        #pragma unroll
        for (int off = 16; off; off >>= 1) su += __shfl_xor(su, off, 32);
        wts[h][r] = e / su;
    }
    __syncthreads();

    // combine with h-pair sharing: hp = wave (0..3), d2 = lane*2;
    // one 4B mrows read feeds h=hp and h=hp+4. Same per-(h,d) accumulation
    // order as R13 -> bit-identical u.
    {
        const int hp = wave;
        const int d2 = lane << 1;
        float a0 = 0.f, a1 = 0.f, a2 = 0.f, a3 = 0.f;
        #pragma unroll
        for (int r = 0; r < 32; ++r) {
            float w0 = wts[hp][r];
            float w1 = wts[hp + 4][r];
            unsigned mv = *(const unsigned*)&mrows[r][d2];
            float m0 = b2f((short)(mv & 0xffffu));
            float m1 = b2f((short)(mv >> 16));
            a0 += w0 * m0; a1 += w0 * m1;
            a2 += w1 * m0; a3 += w1 * m1;
        }
        unsigned p0 = ((unsigned)(unsigned short)f2b(a0)) |
                      (((unsigned)(unsigned short)f2b(a1)) << 16);
        unsigned p1 = ((unsigned)(unsigned short)f2b(a2)) |
                      (((unsigned)(unsigned short)f2b(a3)) << 16);
        *(unsigned*)(u + (size_t)bq * 1024 + (hp << 7) + d2) = p0;
        *(unsigned*)(u + (size_t)bq * 1024 + ((hp + 4) << 7) + d2) = p1;
    }
}

// ---------------------------------------------------------------------------
// tail_fused (R13 verbatim): per block = 4 batches.
// ---------------------------------------------------------------------------
__global__ __launch_bounds__(256) void tail_fused(
    const short* __restrict__ ybf, const short* __restrict__ S2t,
    const short* __restrict__ VP2z, const float* __restrict__ pe,
    const int* __restrict__ rel, float* __restrict__ outp)
{
    __shared__ short yL[48][136];
    __shared__ short TL[48][136];
    __shared__ short Bs[64][136];
    __shared__ float sw[4][10][3];
    __shared__ float peL[960];
    __shared__ int   selS[120];

    const int tid  = threadIdx.x;
    const int wave = tid >> 6, lane = tid & 63;
    const int row16 = lane & 15, kq8 = (lane >> 4) << 3, rb4 = (lane >> 4) << 2;
    const int B0row = blockIdx.x * 40;

    for (int g = tid; g < 640; g += 256) {
        int r = g >> 4, c8 = (g & 15) << 3;
        *(bf16x8v*)&yL[r][c8] = *(const bf16x8v*)(ybf + (size_t)(B0row + r) * 128 + c8);
    }
    for (int g = tid; g < 1088; g += 256) ((short*)yL)[40 * 136 + g] = 0;
    for (int g = tid; g < 400; g += 256) {
        int v = rel[(size_t)blockIdx.x * 400 + g];
        if (v >= 0) {
            int bb = g / 100, rem = g - bb * 100;
            int q = rem / 10, k = rem - q * 10;
            selS[bb * 30 + q * 3 + v] = k;
        }
    }
    for (int g = tid; g < 960; g += 256) peL[g] = pe[(size_t)blockIdx.x * 960 + g];
    __syncthreads();

    bf16x8v af[3][4];
    #pragma unroll
    for (int mt = 0; mt < 3; ++mt)
        #pragma unroll
        for (int kk = 0; kk < 4; ++kk)
            af[mt][kk] = *(const bf16x8v*)&yL[(mt << 4) + row16][(kk << 5) + kq8];

    f32x4 acc_out[5] = {};

    for (int h = 0; h < 8; ++h) {
        #pragma unroll
        for (int dh = 0; dh < 2; ++dh) {
            __syncthreads();
            #pragma unroll
            for (int i = 0; i < 4; ++i) {
                int g = (i << 8) + tid;
                int r = g >> 4, c8 = (g & 15) << 3;
                *(bf16x8v*)&Bs[r][c8] =
                    *(const bf16x8v*)(S2t + (size_t)(h * 128 + dh * 64 + r) * 128 + c8);
            }
            __syncthreads();
            bf16x8v bfr[4];
            #pragma unroll
            for (int kk = 0; kk < 4; ++kk)
                bfr[kk] = *(const bf16x8v*)&Bs[(wave << 4) + row16][(kk << 5) + kq8];
            f32x4 gacc[3] = {};
            #pragma unroll
            for (int mt = 0; mt < 3; ++mt)
                #pragma unroll
                for (int kk = 0; kk < 4; ++kk)
                    gacc[mt] = __builtin_amdgcn_mfma_f32_16x16x32_bf16(
                        af[mt][kk], bfr[kk], gacc[mt], 0, 0, 0);
            #pragma unroll
            for (int mt = 0; mt < 3; ++mt)
                #pragma unroll
                for (int r = 0; r < 4; ++r) {
                    int a = (mt << 4) + rb4 + r;
                    if (a < 40) TL[a][(dh << 6) + (wave << 4) + row16] = f2b(gacc[mt][r]);
                }
        }
        __syncthreads();

        if (tid < 120) {
            int bb = tid / 30, rem = tid - bb * 30, q = rem / 3, r = rem - q * 3;
            int k = selS[bb * 30 + q * 3 + r];
            const short* gq = &TL[bb * 10 + q][0];
            const short* yk = &yL[bb * 10 + k][0];
            float s = 0.f;
            #pragma unroll
            for (int d = 0; d < 128; d += 4) {
                short4v gv = *(const short4v*)(gq + d);
                short4v yv = *(const short4v*)(yk + d);
                s += b2f(gv.x) * b2f(yv.x) + b2f(gv.y) * b2f(yv.y)
                   + b2f(gv.z) * b2f(yv.z) + b2f(gv.w) * b2f(yv.w);
            }
            sw[bb][q][r] = s + peL[bb * 240 + q * 24 + r * 8 + h];
        }
        __syncthreads();
        if (tid < 40) {
            int bb = tid / 10, q = tid - bb * 10;
            float s0 = sw[bb][q][0], s1 = sw[bb][q][1], s2 = sw[bb][q][2];
            float mx = fmaxf(s0, fmaxf(s1, s2));
            float e0 = __expf(s0 - mx), e1 = __expf(s1 - mx), e2 = __expf(s2 - mx);
            float inv = 1.f / (e0 + e1 + e2);
            sw[bb][q][0] = e0 * inv; sw[bb][q][1] = e1 * inv; sw[bb][q][2] = e2 * inv;
        }

        #pragma unroll
        for (int dh = 0; dh < 2; ++dh) {
            __syncthreads();
            #pragma unroll
            for (int i = 0; i < 4; ++i) {
                int g = (i << 8) + tid;
                int r = g >> 4, c8 = (g & 15) << 3;
                *(bf16x8v*)&Bs[r][c8] =
                    *(const bf16x8v*)(VP2z + (size_t)(h * 128 + dh * 64 + r) * 128 + c8);
            }
            __syncthreads();
            bf16x8v bfr[4];
            #pragma unroll
            for (int kk = 0; kk < 4; ++kk)
                bfr[kk] = *(const bf16x8v*)&Bs[(wave << 4) + row16][(kk << 5) + kq8];
            f32x4 zacc[3] = {};
            #pragma unroll
            for (int mt = 0; mt < 3; ++mt)
                #pragma unroll
                for (int kk = 0; kk < 4; ++kk)
                    zacc[mt] = __builtin_amdgcn_mfma_f32_16x16x32_bf16(
                        af[mt][kk], bfr[kk], zacc[mt], 0, 0, 0);
            #pragma unroll
            for (int mt = 0; mt < 3; ++mt)
                #pragma unroll
                for (int r = 0; r < 4; ++r) {
                    int a = (mt << 4) + rb4 + r;
                    if (a < 40) TL[a][(dh << 6) + (wave << 4) + row16] = f2b(zacc[mt][r]);
                }
        }
        __syncthreads();

        #pragma unroll
        for (int i = 0; i < 5; ++i) {
            int g = (i << 8) + tid;
            int a = g >> 5, d4 = (g & 31) << 2;
            int bb = (a * 205) >> 11, q = a - bb * 10;
            int k0 = selS[bb * 30 + q * 3 + 0];
            int k1 = selS[bb * 30 + q * 3 + 1];
            int k2 = selS[bb * 30 + q * 3 + 2];
            float w0 = sw[bb][q][0], w1 = sw[bb][q][1], w2 = sw[bb][q][2];
            short4v z0 = *(const short4v*)&TL[bb * 10 + k0][d4];
            short4v z1 = *(const short4v*)&TL[bb * 10 + k1][d4];
            short4v z2 = *(const short4v*)&TL[bb * 10 + k2][d4];
            acc_out[i].x += w0 * b2f(z0.x) + w1 * b2f(z1.x) + w2 * b2f(z2.x);
            acc_out[i].y += w0 * b2f(z0.y) + w1 * b2f(z1.y) + w2 * b2f(z2.y);
            acc_out[i].z += w0 * b2f(z0.z) + w1 * b2f(z1.z) + w2 * b2f(z2.z);
            acc_out[i].w += w0 * b2f(z0.w) + w1 * b2f(z1.w) + w2 * b2f(z2.w);
        }
    }

    #pragma unroll
    for (int i = 0; i < 5; ++i) {
        int g = (i << 8) + tid;
        int a = g >> 5, d4 = (g & 31) << 2;
        *(f32x4*)(outp + (size_t)(B0row + a) * 128 + d4) = acc_out[i];
    }
}

// ---------------------------------------------------------------------------
extern "C" void kernel_launch(void* const* d_in, const int* in_sizes, int n_in,
                              void* d_out, int out_size, void* d_ws, size_t ws_size,
                              hipStream_t stream)
{
    const float* a_token = (const float*)d_in[0];
    const float* m_token = (const float*)d_in[1];
    const float* a2m_pe  = (const float*)d_in[2];
    const float* a_pe    = (const float*)d_in[3];
    const float* Wq      = (const float*)d_in[4];
    const float* Wk      = (const float*)d_in[5];
    const float* Wv      = (const float*)d_in[6];
    const float* Wcp     = (const float*)d_in[7];
    const float* Wc      = (const float*)d_in[8];
    const float* Wsp     = (const float*)d_in[9];
    const int*   a2m_rel = (const int*)d_in[10];
    const int*   a_rel   = (const int*)d_in[11];

    char* ws = (char*)d_ws;
    short* S1t  = (short*)(ws + 0);
    short* VP1t = (short*)(ws + 262144);
    short* S2t  = (short*)(ws + 524288);
    short* VP2z = (short*)(ws + 786432);
    short* buf1 = (short*)(ws + 1048576);                      // qS
    short* buf2 = (short*)(ws + 1048576 + 58982400ull);        // u
    short* ybf  = (short*)(ws + 1048576 + 2ull * 58982400ull); // y bf16
    short* abf  = (short*)(ws + 126386176ull);                 // a_token bf16
    float* outp = (float*)d_out;

    precompute_mats<<<dim3(2048), dim3(256), 0, stream>>>(
        Wq, Wk, Wv, Wcp, Wc, Wsp, S1t, VP1t, S2t, VP2z);

    conv_bf16<<<dim3(1800), dim3(256), 0, stream>>>(a_token, abf);

    // qS = a @ S1   [28800,1024], K=128
    gemm_bt<false><<<dim3(8, 225), dim3(256), 0, stream>>>(
        abf, S1t, (void*)buf1, BQ_N, 1024, 128);

    attn_cross<<<dim3(BQ_N), dim3(256), 0, stream>>>(
        m_token, buf1, a2m_pe, a2m_rel, buf2);

    // y = u @ VP1   [28800,128], K=1024 -- 512-thread variant (2 waves/SIMD)
    gemm_bt512<<<dim3(1, 225), dim3(512), 0, stream>>>(
        buf2, VP1t, ybf, BQ_N, 128, 1024);

    // fused tail (R13)
    tail_fused<<<dim3(720), dim3(256), 0, stream>>>(
        ybf, S2t, VP2z, a_pe, a_rel, outp);
}